// Round 4
// baseline (1484.014 us; speedup 1.0000x reference)
//
#include <hip/hip_runtime.h>
#include <math.h>

#define ND 128
#define ED 64
#define LN_EPS 1e-5f
#define SXF 330   // edge LDS row stride (fp32): 330 ≡ 10 mod 32 -> conflict-free b128
#define GSF 132   // gru  LDS row stride (fp32): 132 ≡ 4 mod 32 -> 2-way (free)

typedef __attribute__((ext_vector_type(8))) short bf16x8;
typedef __attribute__((ext_vector_type(4))) float f32x4;

__device__ __forceinline__ unsigned short f2bf(float f) {
    union { float f; unsigned u; } v; v.f = f;
    unsigned r = v.u + 0x7FFFu + ((v.u >> 16) & 1u);   // RNE
    return (unsigned short)(r >> 16);
}
__device__ __forceinline__ float bf2f(unsigned short h) {
    union { unsigned u; float f; } v; v.u = ((unsigned)h) << 16;
    return v.f;
}
__device__ __forceinline__ float sigmoidf_(float x) { return 1.f / (1.f + expf(-x)); }

__device__ __forceinline__ void split8(const float* p, bf16x8& hi, bf16x8& lo) {
    float4 v0 = *(const float4*)p;
    float4 v1 = *(const float4*)(p + 4);
    float xv[8] = {v0.x, v0.y, v0.z, v0.w, v1.x, v1.y, v1.z, v1.w};
    #pragma unroll
    for (int j = 0; j < 8; ++j) {
        unsigned short h = f2bf(xv[j]);
        hi[j] = (short)h;
        lo[j] = (short)f2bf(xv[j] - bf2f(h));
    }
}

// ---- weight conversion: fp32 -> bf16 hi/lo pairs (+transpose for W1,W2) ----
__global__ void convert_kernel(const float* __restrict__ W1, const float* __restrict__ W2,
                               const float* __restrict__ Wih, const float* __restrict__ Whh,
                               unsigned short* __restrict__ W1h, unsigned short* __restrict__ W1l,
                               unsigned short* __restrict__ W2h, unsigned short* __restrict__ W2l,
                               unsigned short* __restrict__ Wihh, unsigned short* __restrict__ Wihl,
                               unsigned short* __restrict__ Whhh, unsigned short* __restrict__ Whhl)
{
    int idx = blockIdx.x * 256 + threadIdx.x;
    float v; unsigned short *ph, *pl; int o;
    if (idx < 40960)        { int n = idx / 320, k = idx - n * 320; v = W1[k * 128 + n]; ph = W1h; pl = W1l; o = idx; }
    else if (idx < 57344)   { int i2 = idx - 40960; int n = i2 >> 7, k = i2 & 127; v = W2[k * 128 + n]; ph = W2h; pl = W2l; o = i2; }
    else if (idx < 106496)  { int i3 = idx - 57344;  v = Wih[i3]; ph = Wihh; pl = Wihl; o = i3; }
    else                    { int i4 = idx - 106496; v = Whh[i4]; ph = Whhh; pl = Whhl; o = i4; }
    unsigned short h = f2bf(v);
    ph[o] = h;
    pl[o] = f2bf(v - bf2f(h));
}

// ---- CSR-style dst-sort: histogram -> scan -> scatter-rank ----
__global__ void hist_kernel(const int* __restrict__ eidx, int* __restrict__ cnt, int E) {
    int i = blockIdx.x * 256 + threadIdx.x;
    if (i < E) atomicAdd(&cnt[eidx[E + i]], 1);
}

__global__ __launch_bounds__(1024)
void scan_kernel(const int* __restrict__ cnt, int* __restrict__ woff, int N) {
    __shared__ int part[1024];
    const int t = threadIdx.x;
    const int CH = 40;             // 1024*40 = 40960 >= 40000
    int base = t * CH;
    int s = 0;
    for (int i = 0; i < CH; ++i) { int idx = base + i; if (idx < N) s += cnt[idx]; }
    part[t] = s;
    __syncthreads();
    for (int d = 1; d < 1024; d <<= 1) {   // Hillis-Steele inclusive
        int v = (t >= d) ? part[t - d] : 0;
        __syncthreads();
        part[t] += v;
        __syncthreads();
    }
    int run = (t == 0) ? 0 : part[t - 1];  // exclusive
    for (int i = 0; i < CH; ++i) {
        int idx = base + i;
        if (idx < N) { woff[idx] = run; run += cnt[idx]; }
    }
}

__global__ void scatter_kernel(const int* __restrict__ eidx, int* __restrict__ woff,
                               int* __restrict__ perm, int E) {
    int i = blockIdx.x * 256 + threadIdx.x;
    if (i < E) {
        int p = atomicAdd(&woff[eidx[E + i]], 1);
        perm[p] = i;
    }
}

// ---------------- edge message kernel (split-bf16 MFMA + sorted segment scatter) ----------------
// 256 thr = 4 waves; 32 dst-sorted edges/block. Wave w: M-tile mt=w&1, N-half nh=w>>1.
__global__ __launch_bounds__(256, 3)
void edge_kernel(const float* __restrict__ nf, const int* __restrict__ eidx,
                 const float* __restrict__ ef, const int* __restrict__ perm,
                 const unsigned short* __restrict__ W1h, const unsigned short* __restrict__ W1l,
                 const float* __restrict__ b1,
                 const float* __restrict__ ln_g, const float* __restrict__ ln_b,
                 const unsigned short* __restrict__ W2h, const unsigned short* __restrict__ W2l,
                 const float* __restrict__ b2,
                 const float* __restrict__ gate_w, const float* __restrict__ gate_b,
                 float* __restrict__ agg, int E)
{
    __shared__ float sx[32 * SXF];          // 41.25 KB; reused for h and then messages
    __shared__ float sred[2][2][16][2];     // LN partials [mt][nh][row][p1,p2]
    __shared__ int se_s[32], ssrc_s[32], sdst_s[32];

    const int tid  = threadIdx.x;
    const int lane = tid & 63;
    const int w    = tid >> 6;
    const int mt   = w & 1, nh = w >> 1;
    const int c    = lane & 15;
    const int quad = lane >> 4;
    const int e0   = blockIdx.x * 32;

    if (tid < 32) {
        int e = perm[e0 + tid];
        se_s[tid]   = e;
        ssrc_s[tid] = eidx[e];
        sdst_s[tid] = eidx[E + e];
    }
    __syncthreads();

    // ---- stage 32 rows x 320 fp32: [nf[src] | nf[dst] | ef] ----
    {
        const int r = tid >> 3, q = tid & 7;
        const float* srow = nf + (size_t)ssrc_s[r] * ND;
        const float* drow = nf + (size_t)sdst_s[r] * ND;
        const float* erow = ef + (size_t)se_s[r] * ED;
        float* dp = sx + r * SXF;
        #pragma unroll
        for (int i = 0; i < 10; ++i) {
            int f4 = q + 8 * i;
            const float* s = (f4 < 32) ? (srow + f4 * 4)
                           : (f4 < 64) ? (drow + (f4 - 32) * 4)
                                       : (erow + (f4 - 64) * 4);
            *(float4*)(dp + f4 * 4) = *(const float4*)s;
        }
    }
    __syncthreads();

    const int myrow = 16 * mt + c;

    // ---- edge gate ----
    float g;
    {
        float gp = 0.f;
        const float* er = sx + myrow * SXF + 256 + quad * 16;
        #pragma unroll
        for (int k = 0; k < 16; ++k) gp = fmaf(er[k], gate_w[quad * 16 + k], gp);
        gp += __shfl_xor(gp, 16);
        gp += __shfl_xor(gp, 32);
        g = sigmoidf_(gp + gate_b[0]);
    }

    // ---- GEMM1: [16x320]@[320x128], 3-term split ----
    f32x4 acc[4];
    #pragma unroll
    for (int t = 0; t < 4; ++t) acc[t] = (f32x4){0.f, 0.f, 0.f, 0.f};
    #pragma unroll
    for (int ks = 0; ks < 10; ++ks) {
        bf16x8 ahi, alo;
        split8(sx + myrow * SXF + ks * 32 + quad * 8, ahi, alo);
        #pragma unroll
        for (int ntl = 0; ntl < 4; ++ntl) {
            int col = (4 * nh + ntl) * 16 + c;
            bf16x8 bh = *(const bf16x8*)(W1h + col * 320 + ks * 32 + quad * 8);
            bf16x8 bl = *(const bf16x8*)(W1l + col * 320 + ks * 32 + quad * 8);
            acc[ntl] = __builtin_amdgcn_mfma_f32_16x16x32_bf16(ahi, bh, acc[ntl], 0, 0, 0);
            acc[ntl] = __builtin_amdgcn_mfma_f32_16x16x32_bf16(alo, bh, acc[ntl], 0, 0, 0);
            acc[ntl] = __builtin_amdgcn_mfma_f32_16x16x32_bf16(ahi, bl, acc[ntl], 0, 0, 0);
        }
    }

    // ---- bias + LayerNorm + ReLU, h -> LDS fp32 ----
    float b1v[4], gv[4], bv[4];
    #pragma unroll
    for (int ntl = 0; ntl < 4; ++ntl) {
        int col = (4 * nh + ntl) * 16 + c;
        b1v[ntl] = b1[col]; gv[ntl] = ln_g[col]; bv[ntl] = ln_b[col];
    }
    float p1[4] = {0, 0, 0, 0}, p2[4] = {0, 0, 0, 0};
    #pragma unroll
    for (int ntl = 0; ntl < 4; ++ntl)
        #pragma unroll
        for (int r = 0; r < 4; ++r) {
            float vv = acc[ntl][r] + b1v[ntl];
            acc[ntl][r] = vv;
            p1[r] += vv; p2[r] += vv * vv;
        }
    #pragma unroll
    for (int m = 1; m < 16; m <<= 1)
        #pragma unroll
        for (int r = 0; r < 4; ++r) {
            p1[r] += __shfl_xor(p1[r], m);
            p2[r] += __shfl_xor(p2[r], m);
        }
    if (c == 0) {
        #pragma unroll
        for (int r = 0; r < 4; ++r) {
            sred[mt][nh][quad * 4 + r][0] = p1[r];
            sred[mt][nh][quad * 4 + r][1] = p2[r];
        }
    }
    __syncthreads();
    float mu[4], rs[4];
    #pragma unroll
    for (int r = 0; r < 4; ++r) {
        int row = quad * 4 + r;
        float t1 = sred[mt][0][row][0] + sred[mt][1][row][0];
        float t2 = sred[mt][0][row][1] + sred[mt][1][row][1];
        mu[r] = t1 * (1.f / 128.f);
        float var = t2 * (1.f / 128.f) - mu[r] * mu[r];
        rs[r] = rsqrtf(var + LN_EPS);
    }
    #pragma unroll
    for (int ntl = 0; ntl < 4; ++ntl)
        #pragma unroll
        for (int r = 0; r < 4; ++r) {
            float vv = (acc[ntl][r] - mu[r]) * rs[r] * gv[ntl] + bv[ntl];
            vv = vv > 0.f ? vv : 0.f;
            sx[(16 * mt + quad * 4 + r) * SXF + (4 * nh + ntl) * 16 + c] = vv;
        }
    __syncthreads();

    // ---- GEMM2: [16x128]@[128x128], 3-term split ----
    f32x4 acc2[4];
    #pragma unroll
    for (int t = 0; t < 4; ++t) acc2[t] = (f32x4){0.f, 0.f, 0.f, 0.f};
    #pragma unroll
    for (int ks = 0; ks < 4; ++ks) {
        bf16x8 ahi, alo;
        split8(sx + myrow * SXF + ks * 32 + quad * 8, ahi, alo);
        #pragma unroll
        for (int ntl = 0; ntl < 4; ++ntl) {
            int col = (4 * nh + ntl) * 16 + c;
            bf16x8 bh = *(const bf16x8*)(W2h + col * 128 + ks * 32 + quad * 8);
            bf16x8 bl = *(const bf16x8*)(W2l + col * 128 + ks * 32 + quad * 8);
            acc2[ntl] = __builtin_amdgcn_mfma_f32_16x16x32_bf16(ahi, bh, acc2[ntl], 0, 0, 0);
            acc2[ntl] = __builtin_amdgcn_mfma_f32_16x16x32_bf16(alo, bh, acc2[ntl], 0, 0, 0);
            acc2[ntl] = __builtin_amdgcn_mfma_f32_16x16x32_bf16(ahi, bl, acc2[ntl], 0, 0, 0);
        }
    }
    __syncthreads();   // tile dead: safe to overwrite with messages

    // ---- gated messages -> LDS ----
    float g4[4];
    #pragma unroll
    for (int r = 0; r < 4; ++r) g4[r] = __shfl(g, quad * 4 + r);
    #pragma unroll
    for (int ntl = 0; ntl < 4; ++ntl) {
        int col = (4 * nh + ntl) * 16 + c;
        float b2v = b2[col];
        #pragma unroll
        for (int r = 0; r < 4; ++r)
            sx[(16 * mt + quad * 4 + r) * SXF + col] = (acc2[ntl][r] + b2v) * g4[r];
    }
    __syncthreads();

    // ---- segment reduction over sorted dst: ~3 atomics/col instead of 32 ----
    if (tid < 128) {
        const int col = tid;
        float run = sx[col];
        int prev = sdst_s[0];
        #pragma unroll 4
        for (int r = 1; r < 32; ++r) {
            int d = sdst_s[r];                 // wave-uniform -> no divergence
            float v = sx[r * SXF + col];
            if (d == prev) run += v;
            else {
                atomicAdd(agg + (size_t)prev * ND + col, run);
                run = v; prev = d;
            }
        }
        atomicAdd(agg + (size_t)prev * ND + col, run);
    }
}

// ---------------- GRU kernel (split-bf16 MFMA) ----------------
// (256,1): 96 accumulator VGPRs + fragments need >128 regs — avoid spill.
__global__ __launch_bounds__(256, 1)
void gru_kernel(const float* __restrict__ agg, const float* __restrict__ nf,
                const unsigned short* __restrict__ Wihh, const unsigned short* __restrict__ Wihl,
                const float* __restrict__ b_ih,
                const unsigned short* __restrict__ Whhh, const unsigned short* __restrict__ Whhl,
                const float* __restrict__ b_hh,
                float* __restrict__ out)
{
    __shared__ float sa[32 * GSF];
    __shared__ float sh[32 * GSF];

    const int tid  = threadIdx.x;
    const int lane = tid & 63;
    const int w    = tid >> 6;
    const int c    = lane & 15;
    const int quad = lane >> 4;
    const int n0   = blockIdx.x * 32;

    {
        const int r = tid >> 3, q = tid & 7;
        const float* arow = agg + (size_t)(n0 + r) * ND;
        const float* hrow = nf  + (size_t)(n0 + r) * ND;
        #pragma unroll
        for (int i = 0; i < 4; ++i) {
            int f4 = q + 8 * i;
            *(float4*)(sa + r * GSF + f4 * 4) = *(const float4*)(arow + f4 * 4);
            *(float4*)(sh + r * GSF + f4 * 4) = *(const float4*)(hrow + f4 * 4);
        }
    }
    __syncthreads();

    f32x4 aI[2][6], aH[2][6];
    #pragma unroll
    for (int mt = 0; mt < 2; ++mt)
        #pragma unroll
        for (int j = 0; j < 6; ++j) {
            aI[mt][j] = (f32x4){0.f, 0.f, 0.f, 0.f};
            aH[mt][j] = (f32x4){0.f, 0.f, 0.f, 0.f};
        }

    #pragma unroll
    for (int ks = 0; ks < 4; ++ks) {
        bf16x8 fah[2], fal[2], fhh[2], fhl[2];
        #pragma unroll
        for (int mt = 0; mt < 2; ++mt) {
            split8(sa + (mt * 16 + c) * GSF + ks * 32 + quad * 8, fah[mt], fal[mt]);
            split8(sh + (mt * 16 + c) * GSF + ks * 32 + quad * 8, fhh[mt], fhl[mt]);
        }
        #pragma unroll
        for (int gg = 0; gg < 3; ++gg)
            #pragma unroll
            for (int nt = 0; nt < 2; ++nt) {
                int coln = gg * 128 + 32 * w + nt * 16 + c;
                bf16x8 bIh = *(const bf16x8*)(Wihh + coln * 128 + ks * 32 + quad * 8);
                bf16x8 bIl = *(const bf16x8*)(Wihl + coln * 128 + ks * 32 + quad * 8);
                bf16x8 bHh = *(const bf16x8*)(Whhh + coln * 128 + ks * 32 + quad * 8);
                bf16x8 bHl = *(const bf16x8*)(Whhl + coln * 128 + ks * 32 + quad * 8);
                #pragma unroll
                for (int mt = 0; mt < 2; ++mt) {
                    int j = gg * 2 + nt;
                    aI[mt][j] = __builtin_amdgcn_mfma_f32_16x16x32_bf16(fah[mt], bIh, aI[mt][j], 0, 0, 0);
                    aI[mt][j] = __builtin_amdgcn_mfma_f32_16x16x32_bf16(fal[mt], bIh, aI[mt][j], 0, 0, 0);
                    aI[mt][j] = __builtin_amdgcn_mfma_f32_16x16x32_bf16(fah[mt], bIl, aI[mt][j], 0, 0, 0);
                    aH[mt][j] = __builtin_amdgcn_mfma_f32_16x16x32_bf16(fhh[mt], bHh, aH[mt][j], 0, 0, 0);
                    aH[mt][j] = __builtin_amdgcn_mfma_f32_16x16x32_bf16(fhl[mt], bHh, aH[mt][j], 0, 0, 0);
                    aH[mt][j] = __builtin_amdgcn_mfma_f32_16x16x32_bf16(fhh[mt], bHl, aH[mt][j], 0, 0, 0);
                }
            }
    }

    #pragma unroll
    for (int nt = 0; nt < 2; ++nt) {
        int col = 32 * w + nt * 16 + c;
        float bir = b_ih[col], biz = b_ih[128 + col], bin = b_ih[256 + col];
        float bhr = b_hh[col], bhz = b_hh[128 + col], bhn = b_hh[256 + col];
        #pragma unroll
        for (int mt = 0; mt < 2; ++mt)
            #pragma unroll
            for (int r = 0; r < 4; ++r) {
                int row = mt * 16 + quad * 4 + r;
                float rr = sigmoidf_(aI[mt][0 + nt][r] + bir + aH[mt][0 + nt][r] + bhr);
                float zz = sigmoidf_(aI[mt][2 + nt][r] + biz + aH[mt][2 + nt][r] + bhz);
                float nn = tanhf(aI[mt][4 + nt][r] + bin + rr * (aH[mt][4 + nt][r] + bhn));
                float hp = sh[row * GSF + col];
                out[(size_t)(n0 + row) * ND + col] = (1.f - zz) * nn + zz * hp;
            }
    }
}

extern "C" void kernel_launch(void* const* d_in, const int* in_sizes, int n_in,
                              void* d_out, int out_size, void* d_ws, size_t ws_size,
                              hipStream_t stream) {
    const float* nf     = (const float*)d_in[0];
    const int*   eidx   = (const int*)  d_in[1];
    const float* ef     = (const float*)d_in[2];
    const float* W1     = (const float*)d_in[3];
    const float* b1     = (const float*)d_in[4];
    const float* ln_g   = (const float*)d_in[5];
    const float* ln_b   = (const float*)d_in[6];
    const float* W2     = (const float*)d_in[7];
    const float* b2     = (const float*)d_in[8];
    const float* gate_w = (const float*)d_in[9];
    const float* gate_b = (const float*)d_in[10];
    const float* W_ih   = (const float*)d_in[11];
    const float* b_ih   = (const float*)d_in[12];
    const float* W_hh   = (const float*)d_in[13];
    const float* b_hh   = (const float*)d_in[14];
    float* out = (float*)d_out;

    const int N = in_sizes[0] / ND;   // 40000
    const int E = in_sizes[1] / 2;    // 640000

    char* ws = (char*)d_ws;
    float* agg = (float*)ws;                      ws += (size_t)N * ND * 4;   // 20.48 MB
    unsigned short* W1h  = (unsigned short*)ws;   ws += 40960 * 2;
    unsigned short* W1l  = (unsigned short*)ws;   ws += 40960 * 2;
    unsigned short* W2h  = (unsigned short*)ws;   ws += 16384 * 2;
    unsigned short* W2l  = (unsigned short*)ws;   ws += 16384 * 2;
    unsigned short* Wihh = (unsigned short*)ws;   ws += 49152 * 2;
    unsigned short* Wihl = (unsigned short*)ws;   ws += 49152 * 2;
    unsigned short* Whhh = (unsigned short*)ws;   ws += 49152 * 2;
    unsigned short* Whhl = (unsigned short*)ws;   ws += 49152 * 2;
    int* cnt  = (int*)ws;                         ws += 40960 * 4;
    int* woff = (int*)ws;                         ws += 40960 * 4;
    int* perm = (int*)ws;                         ws += (size_t)E * 4;        // 2.56 MB

    hipMemsetAsync(agg, 0, (size_t)N * ND * 4, stream);
    hipMemsetAsync(cnt, 0, (size_t)N * 4, stream);
    convert_kernel<<<608, 256, 0, stream>>>(W1, W2, W_ih, W_hh,
                                            W1h, W1l, W2h, W2l, Wihh, Wihl, Whhh, Whhl);
    hist_kernel<<<(E + 255) / 256, 256, 0, stream>>>(eidx, cnt, E);
    scan_kernel<<<1, 1024, 0, stream>>>(cnt, woff, N);
    scatter_kernel<<<(E + 255) / 256, 256, 0, stream>>>(eidx, woff, perm, E);
    edge_kernel<<<E / 32, 256, 0, stream>>>(nf, eidx, ef, perm, W1h, W1l, b1, ln_g, ln_b,
                                            W2h, W2l, b2, gate_w, gate_b, agg, E);
    gru_kernel<<<N / 32, 256, 0, stream>>>(agg, nf, Wihh, Wihl, b_ih, Whhh, Whhl, b_hh, out);
}

// Round 5
// 649.383 us; speedup vs baseline: 2.2853x; 2.2853x over previous
//
#include <hip/hip_runtime.h>
#include <math.h>

#define ND 128
#define ED 64
#define LN_EPS 1e-5f
#define TE 64        // edges per block (edge kernel)
#define SXH 328      // edge LDS row stride (halves): 656B/row; as float stride = 164 dw
#define GSH 136      // gru f16 LDS row stride (halves)
#define GSF 132      // gru fp32 LDS row stride (floats)

typedef _Float16 f16;
typedef __attribute__((ext_vector_type(8))) _Float16 f16x8;
typedef __attribute__((ext_vector_type(4))) _Float16 f16x4;
typedef __attribute__((ext_vector_type(4))) float f32x4;

__device__ __forceinline__ float sigmoidf_(float x) { return 1.f / (1.f + expf(-x)); }

// ---- weight conversion: fp32 -> f16 (+transpose for W1,W2) ----
// W1f[n*320+k] = W1[k*128+n]; W2f[n*128+k] = W2[k*128+n]; Wih/Whh straight.
__global__ void convert_kernel(const float* __restrict__ W1, const float* __restrict__ W2,
                               const float* __restrict__ Wih, const float* __restrict__ Whh,
                               f16* __restrict__ W1f, f16* __restrict__ W2f,
                               f16* __restrict__ Wihf, f16* __restrict__ Whhf)
{
    int idx = blockIdx.x * 256 + threadIdx.x;
    if (idx < 40960) {
        int n = idx / 320, k = idx - n * 320;
        W1f[idx] = (f16)W1[k * 128 + n];
    } else if (idx < 57344) {
        int i2 = idx - 40960; int n = i2 >> 7, k = i2 & 127;
        W2f[i2] = (f16)W2[k * 128 + n];
    } else if (idx < 106496) {
        int i3 = idx - 57344;  Wihf[i3] = (f16)Wih[i3];
    } else if (idx < 155648) {
        int i4 = idx - 106496; Whhf[i4] = (f16)Whh[i4];
    }
}

// ---- CSR-style dst-sort: histogram -> scan -> scatter-rank ----
__global__ void hist_kernel(const int* __restrict__ eidx, int* __restrict__ cnt, int E) {
    int i = blockIdx.x * 256 + threadIdx.x;
    if (i < E) atomicAdd(&cnt[eidx[E + i]], 1);
}

__global__ __launch_bounds__(1024)
void scan_kernel(const int* __restrict__ cnt, int* __restrict__ woff, int N) {
    __shared__ int part[1024];
    const int t = threadIdx.x;
    const int CH = 40;
    int base = t * CH;
    int s = 0;
    for (int i = 0; i < CH; ++i) { int idx = base + i; if (idx < N) s += cnt[idx]; }
    part[t] = s;
    __syncthreads();
    for (int d = 1; d < 1024; d <<= 1) {
        int v = (t >= d) ? part[t - d] : 0;
        __syncthreads();
        part[t] += v;
        __syncthreads();
    }
    int run = (t == 0) ? 0 : part[t - 1];
    for (int i = 0; i < CH; ++i) {
        int idx = base + i;
        if (idx < N) { woff[idx] = run; run += cnt[idx]; }
    }
}

__global__ void scatter_kernel(const int* __restrict__ eidx, int* __restrict__ woff,
                               int* __restrict__ perm, int E) {
    int i = blockIdx.x * 256 + threadIdx.x;
    if (i < E) {
        int p = atomicAdd(&woff[eidx[E + i]], 1);
        perm[p] = i;
    }
}

// ---------------- edge message kernel (f16 MFMA, N-partitioned waves) ----------------
// 256 thr = 4 waves; 64 dst-sorted edges/block. Wave w owns cols [32w,32w+32) (2 N-tiles)
// over ALL 64 edges (4 M-tiles) -> each B-fragment load feeds 4 MFMAs.
__global__ __launch_bounds__(256, 3)
void edge_kernel(const float* __restrict__ nf, const int* __restrict__ eidx,
                 const float* __restrict__ ef, const int* __restrict__ perm,
                 const f16* __restrict__ W1f, const float* __restrict__ b1,
                 const float* __restrict__ ln_g, const float* __restrict__ ln_b,
                 const f16* __restrict__ W2f, const float* __restrict__ b2,
                 const float* __restrict__ gate_w, const float* __restrict__ gate_b,
                 float* __restrict__ agg, int E)
{
    __shared__ f16   sxh[TE * SXH];       // 41 KB: x tile f16; cols[0,128) reused for h', then fp32 messages
    __shared__ float sred[TE * 8];        // LN partials [row][w*2 + {p1,p2}]
    __shared__ float spart[TE][4];        // gate partials
    __shared__ float sg[TE];              // per-edge gate
    __shared__ int   se_s[TE], ssrc_s[TE], sdst_s[TE];

    const int tid  = threadIdx.x;
    const int lane = tid & 63;
    const int w    = __builtin_amdgcn_readfirstlane(tid >> 6);
    const int cb   = 32 * w;              // column base for this wave
    const int c    = lane & 15;
    const int quad = lane >> 4;
    const int e0   = blockIdx.x * TE;

    if (tid < TE) {
        int e = perm[e0 + tid];
        se_s[tid]   = e;
        ssrc_s[tid] = eidx[e];
        sdst_s[tid] = eidx[E + e];
    }
    __syncthreads();   // B0

    // ---- stage 64 rows x 320: [nf[src] | nf[dst] | ef], fp32 -> f16 ----
    {
        const int r = tid >> 2, q = tid & 3;     // 4 threads per row
        const float* srow = nf + (size_t)ssrc_s[r] * ND;
        const float* drow = nf + (size_t)sdst_s[r] * ND;
        const float* erow = ef + (size_t)se_s[r] * ED;
        f16* dp = sxh + r * SXH;
        #pragma unroll
        for (int i = 0; i < 8; ++i) {            // src: cols [0,128)
            int ec = (q + 4 * i) * 4;
            float4 v = *(const float4*)(srow + ec);
            f16x4 h4; h4[0] = (f16)v.x; h4[1] = (f16)v.y; h4[2] = (f16)v.z; h4[3] = (f16)v.w;
            *(f16x4*)(dp + ec) = h4;
        }
        #pragma unroll
        for (int i = 0; i < 8; ++i) {            // dst: cols [128,256)
            int ec = (q + 4 * i) * 4;
            float4 v = *(const float4*)(drow + ec);
            f16x4 h4; h4[0] = (f16)v.x; h4[1] = (f16)v.y; h4[2] = (f16)v.z; h4[3] = (f16)v.w;
            *(f16x4*)(dp + 128 + ec) = h4;
        }
        #pragma unroll
        for (int i = 0; i < 4; ++i) {            // ef: cols [256,320)
            int ec = (q + 4 * i) * 4;
            float4 v = *(const float4*)(erow + ec);
            f16x4 h4; h4[0] = (f16)v.x; h4[1] = (f16)v.y; h4[2] = (f16)v.z; h4[3] = (f16)v.w;
            *(f16x4*)(dp + 256 + ec) = h4;
        }
    }
    __syncthreads();   // B1

    // ---- edge gate partials: thread (row=tid>>2, q=tid&3) covers 16 k ----
    {
        const int grow = tid >> 2, gq = tid & 3;
        const f16* ep = sxh + grow * SXH + 256 + gq * 16;
        f16x8 e0v = *(const f16x8*)ep;
        f16x8 e1v = *(const f16x8*)(ep + 8);
        float p = 0.f;
        #pragma unroll
        for (int j = 0; j < 8; ++j) {
            p = fmaf((float)e0v[j], gate_w[gq * 16 + j], p);
            p = fmaf((float)e1v[j], gate_w[gq * 16 + 8 + j], p);
        }
        spart[grow][gq] = p;
    }
    __syncthreads();   // B2
    if (tid < TE)
        sg[tid] = sigmoidf_(spart[tid][0] + spart[tid][1] + spart[tid][2] + spart[tid][3] + gate_b[0]);

    // ---- GEMM1: [64x320] @ [320x(32 cols/wave)] ----
    f32x4 acc[4][2];
    #pragma unroll
    for (int mt = 0; mt < 4; ++mt)
        #pragma unroll
        for (int nt = 0; nt < 2; ++nt) acc[mt][nt] = (f32x4){0.f, 0.f, 0.f, 0.f};

    #pragma unroll
    for (int ks = 0; ks < 10; ++ks) {
        f16x8 b0 = *(const f16x8*)(W1f + (cb + c) * 320 + ks * 32 + quad * 8);
        f16x8 b1v = *(const f16x8*)(W1f + (cb + 16 + c) * 320 + ks * 32 + quad * 8);
        #pragma unroll
        for (int mt = 0; mt < 4; ++mt) {
            f16x8 a = *(const f16x8*)(sxh + (16 * mt + c) * SXH + ks * 32 + quad * 8);
            acc[mt][0] = __builtin_amdgcn_mfma_f32_16x16x32_f16(a, b0,  acc[mt][0], 0, 0, 0);
            acc[mt][1] = __builtin_amdgcn_mfma_f32_16x16x32_f16(a, b1v, acc[mt][1], 0, 0, 0);
        }
    }

    // ---- bias + LN partials over this wave's 32 cols ----
    float b1c[2], gvc[2], bvc[2], b2c[2];
    #pragma unroll
    for (int nt = 0; nt < 2; ++nt) {
        int col = cb + nt * 16 + c;
        b1c[nt] = b1[col]; gvc[nt] = ln_g[col]; bvc[nt] = ln_b[col]; b2c[nt] = b2[col];
    }
    #pragma unroll
    for (int mt = 0; mt < 4; ++mt) {
        float p1[4] = {0, 0, 0, 0}, p2[4] = {0, 0, 0, 0};
        #pragma unroll
        for (int nt = 0; nt < 2; ++nt)
            #pragma unroll
            for (int r = 0; r < 4; ++r) {
                float vv = acc[mt][nt][r] + b1c[nt];
                acc[mt][nt][r] = vv;
                p1[r] += vv; p2[r] += vv * vv;
            }
        #pragma unroll
        for (int m = 1; m < 16; m <<= 1)
            #pragma unroll
            for (int r = 0; r < 4; ++r) {
                p1[r] += __shfl_xor(p1[r], m);
                p2[r] += __shfl_xor(p2[r], m);
            }
        if (c == 0) {
            #pragma unroll
            for (int r = 0; r < 4; ++r) {
                int row = 16 * mt + 4 * quad + r;
                sred[row * 8 + 2 * w + 0] = p1[r];
                sred[row * 8 + 2 * w + 1] = p2[r];
            }
        }
    }
    __syncthreads();   // B3

    // ---- LN finalize + ReLU; h' (f16) into cols [0,128) ----
    #pragma unroll
    for (int mt = 0; mt < 4; ++mt)
        #pragma unroll
        for (int r = 0; r < 4; ++r) {
            int row = 16 * mt + 4 * quad + r;
            f32x4 lo = *(const f32x4*)(sred + row * 8);
            f32x4 hi = *(const f32x4*)(sred + row * 8 + 4);
            float t1 = lo[0] + lo[2] + hi[0] + hi[2];
            float t2 = lo[1] + lo[3] + hi[1] + hi[3];
            float mu = t1 * (1.f / 128.f);
            float var = t2 * (1.f / 128.f) - mu * mu;
            float rs = rsqrtf(var + LN_EPS);
            #pragma unroll
            for (int nt = 0; nt < 2; ++nt) {
                float vv = (acc[mt][nt][r] - mu) * rs * gvc[nt] + bvc[nt];
                vv = vv > 0.f ? vv : 0.f;
                sxh[row * SXH + cb + nt * 16 + c] = (f16)vv;
            }
        }
    __syncthreads();   // B4

    // ---- GEMM2: [64x128] @ [128x(32 cols/wave)] ----
    f32x4 acc2[4][2];
    #pragma unroll
    for (int mt = 0; mt < 4; ++mt)
        #pragma unroll
        for (int nt = 0; nt < 2; ++nt) acc2[mt][nt] = (f32x4){0.f, 0.f, 0.f, 0.f};
    #pragma unroll
    for (int ks = 0; ks < 4; ++ks) {
        f16x8 b0 = *(const f16x8*)(W2f + (cb + c) * 128 + ks * 32 + quad * 8);
        f16x8 b1v = *(const f16x8*)(W2f + (cb + 16 + c) * 128 + ks * 32 + quad * 8);
        #pragma unroll
        for (int mt = 0; mt < 4; ++mt) {
            f16x8 a = *(const f16x8*)(sxh + (16 * mt + c) * SXH + ks * 32 + quad * 8);
            acc2[mt][0] = __builtin_amdgcn_mfma_f32_16x16x32_f16(a, b0,  acc2[mt][0], 0, 0, 0);
            acc2[mt][1] = __builtin_amdgcn_mfma_f32_16x16x32_f16(a, b1v, acc2[mt][1], 0, 0, 0);
        }
    }
    __syncthreads();   // B5: all h' reads done -> safe to overwrite tile with fp32 messages

    // ---- gated messages (fp32) into LDS ----
    float* smsg = (float*)sxh;   // stride 164 dw per row
    #pragma unroll
    for (int mt = 0; mt < 4; ++mt)
        #pragma unroll
        for (int r = 0; r < 4; ++r) {
            int row = 16 * mt + 4 * quad + r;
            float gr = sg[row];
            #pragma unroll
            for (int nt = 0; nt < 2; ++nt)
                smsg[row * 164 + cb + nt * 16 + c] = (acc2[mt][nt][r] + b2c[nt]) * gr;
        }
    __syncthreads();   // B6

    // ---- segment reduction over sorted dst (~4 atomics/col for 64 edges) ----
    if (tid < 128) {
        const int col = tid;
        float run = smsg[col];
        int prev = sdst_s[0];
        for (int r = 1; r < TE; ++r) {
            int d = sdst_s[r];                 // wave-uniform
            float v = smsg[r * 164 + col];
            if (d == prev) run += v;
            else {
                atomicAdd(agg + (size_t)prev * ND + col, run);
                run = v; prev = d;
            }
        }
        atomicAdd(agg + (size_t)prev * ND + col, run);
    }
}

// ---------------- GRU kernel (f16 MFMA) ----------------
// 256 thr = 4 waves; 32 nodes/block. Wave w owns gate-cols [32w,32w+32).
__global__ __launch_bounds__(256, 2)
void gru_kernel(const float* __restrict__ agg, const float* __restrict__ nf,
                const f16* __restrict__ Wihf, const float* __restrict__ b_ih,
                const f16* __restrict__ Whhf, const float* __restrict__ b_hh,
                float* __restrict__ out)
{
    __shared__ f16   sa[32 * GSH];
    __shared__ f16   sh[32 * GSH];
    __shared__ float shf[32 * GSF];   // fp32 h_prev for the z*h term

    const int tid  = threadIdx.x;
    const int lane = tid & 63;
    const int w    = __builtin_amdgcn_readfirstlane(tid >> 6);
    const int c    = lane & 15;
    const int quad = lane >> 4;
    const int n0   = blockIdx.x * 32;

    {
        const int r = tid >> 3, q = tid & 7;
        const float* arow = agg + (size_t)(n0 + r) * ND;
        const float* hrow = nf  + (size_t)(n0 + r) * ND;
        #pragma unroll
        for (int i = 0; i < 4; ++i) {
            int ec = (q + 8 * i) * 4;
            float4 va = *(const float4*)(arow + ec);
            f16x4 ha; ha[0] = (f16)va.x; ha[1] = (f16)va.y; ha[2] = (f16)va.z; ha[3] = (f16)va.w;
            *(f16x4*)(sa + r * GSH + ec) = ha;
            float4 vh = *(const float4*)(hrow + ec);
            f16x4 hh; hh[0] = (f16)vh.x; hh[1] = (f16)vh.y; hh[2] = (f16)vh.z; hh[3] = (f16)vh.w;
            *(f16x4*)(sh + r * GSH + ec) = hh;
            *(float4*)(shf + r * GSF + ec) = vh;
        }
    }
    __syncthreads();

    f32x4 aI[2][6], aH[2][6];   // [mt][gg*2+nt]
    #pragma unroll
    for (int mt = 0; mt < 2; ++mt)
        #pragma unroll
        for (int j = 0; j < 6; ++j) {
            aI[mt][j] = (f32x4){0.f, 0.f, 0.f, 0.f};
            aH[mt][j] = (f32x4){0.f, 0.f, 0.f, 0.f};
        }

    #pragma unroll
    for (int ks = 0; ks < 4; ++ks) {
        f16x8 fa[2], fh[2];
        #pragma unroll
        for (int mt = 0; mt < 2; ++mt) {
            fa[mt] = *(const f16x8*)(sa + (16 * mt + c) * GSH + ks * 32 + quad * 8);
            fh[mt] = *(const f16x8*)(sh + (16 * mt + c) * GSH + ks * 32 + quad * 8);
        }
        #pragma unroll
        for (int gg = 0; gg < 3; ++gg)
            #pragma unroll
            for (int nt = 0; nt < 2; ++nt) {
                int coln = gg * 128 + 32 * w + nt * 16 + c;
                f16x8 bI = *(const f16x8*)(Wihf + coln * 128 + ks * 32 + quad * 8);
                f16x8 bH = *(const f16x8*)(Whhf + coln * 128 + ks * 32 + quad * 8);
                #pragma unroll
                for (int mt = 0; mt < 2; ++mt) {
                    int j = gg * 2 + nt;
                    aI[mt][j] = __builtin_amdgcn_mfma_f32_16x16x32_f16(fa[mt], bI, aI[mt][j], 0, 0, 0);
                    aH[mt][j] = __builtin_amdgcn_mfma_f32_16x16x32_f16(fh[mt], bH, aH[mt][j], 0, 0, 0);
                }
            }
    }

    #pragma unroll
    for (int nt = 0; nt < 2; ++nt) {
        int col = 32 * w + nt * 16 + c;
        float bir = b_ih[col], biz = b_ih[128 + col], bin = b_ih[256 + col];
        float bhr = b_hh[col], bhz = b_hh[128 + col], bhn = b_hh[256 + col];
        #pragma unroll
        for (int mt = 0; mt < 2; ++mt)
            #pragma unroll
            for (int r = 0; r < 4; ++r) {
                int row = 16 * mt + 4 * quad + r;
                float rr = sigmoidf_(aI[mt][0 + nt][r] + bir + aH[mt][0 + nt][r] + bhr);
                float zz = sigmoidf_(aI[mt][2 + nt][r] + biz + aH[mt][2 + nt][r] + bhz);
                float nn = tanhf(aI[mt][4 + nt][r] + bin + rr * (aH[mt][4 + nt][r] + bhn));
                float hp = shf[row * GSF + col];
                out[(size_t)(n0 + row) * ND + col] = (1.f - zz) * nn + zz * hp;
            }
    }
}

extern "C" void kernel_launch(void* const* d_in, const int* in_sizes, int n_in,
                              void* d_out, int out_size, void* d_ws, size_t ws_size,
                              hipStream_t stream) {
    const float* nf     = (const float*)d_in[0];
    const int*   eidx   = (const int*)  d_in[1];
    const float* ef     = (const float*)d_in[2];
    const float* W1     = (const float*)d_in[3];
    const float* b1     = (const float*)d_in[4];
    const float* ln_g   = (const float*)d_in[5];
    const float* ln_b   = (const float*)d_in[6];
    const float* W2     = (const float*)d_in[7];
    const float* b2     = (const float*)d_in[8];
    const float* gate_w = (const float*)d_in[9];
    const float* gate_b = (const float*)d_in[10];
    const float* W_ih   = (const float*)d_in[11];
    const float* b_ih   = (const float*)d_in[12];
    const float* W_hh   = (const float*)d_in[13];
    const float* b_hh   = (const float*)d_in[14];
    float* out = (float*)d_out;

    const int N = in_sizes[0] / ND;   // 40000
    const int E = in_sizes[1] / 2;    // 640000

    char* ws = (char*)d_ws;
    float* agg = (float*)ws;          ws += (size_t)N * ND * 4;   // 20.48 MB
    f16* W1f  = (f16*)ws;             ws += 40960 * 2;
    f16* W2f  = (f16*)ws;             ws += 16384 * 2;
    f16* Wihf = (f16*)ws;             ws += 49152 * 2;
    f16* Whhf = (f16*)ws;             ws += 49152 * 2;
    int* cnt  = (int*)ws;             ws += 40960 * 4;
    int* woff = (int*)ws;             ws += 40960 * 4;
    int* perm = (int*)ws;             ws += (size_t)E * 4;        // 2.56 MB

    hipMemsetAsync(agg, 0, (size_t)N * ND * 4, stream);
    hipMemsetAsync(cnt, 0, (size_t)N * 4, stream);
    convert_kernel<<<608, 256, 0, stream>>>(W1, W2, W_ih, W_hh, W1f, W2f, Wihf, Whhf);
    hist_kernel<<<(E + 255) / 256, 256, 0, stream>>>(eidx, cnt, E);
    scan_kernel<<<1, 1024, 0, stream>>>(cnt, woff, N);
    scatter_kernel<<<(E + 255) / 256, 256, 0, stream>>>(eidx, woff, perm, E);
    edge_kernel<<<E / TE, 256, 0, stream>>>(nf, eidx, ef, perm, W1f, b1, ln_g, ln_b,
                                            W2f, b2, gate_w, gate_b, agg, E);
    gru_kernel<<<N / 32, 256, 0, stream>>>(agg, nf, Wihf, b_ih, Whhf, b_hh, out);
}